// Round 4
// baseline (158.315 us; speedup 1.0000x reference)
//
#include <hip/hip_runtime.h>
#include <math.h>

#define BB 16
#define NN 1024
#define GG 1024
#define NP1 1025
#define NC 3

// Constants replicated with numpy's exact f32 op sequence (verified absmax=0 R1-R3)
__device__ __forceinline__ void get_consts(float& bnd0, float& bnd1,
                                           float& tb0, float& tb1, float& thr) {
    const float bx0 = (float)(-30.0 + 0.15 / 2.0);
    const float bx1 = (float)(-15.0 + 0.15 / 2.0);
    bnd0 = __fsub_rn(__fmul_rn(0.15f, 0.5f), bx0);
    bnd1 = __fsub_rn(__fmul_rn(0.15f, 0.5f), bx1);
    tb0 = __fmul_rn(2.0f, bnd0); tb1 = __fmul_rn(2.0f, bnd1);
    const float q0 = __fdiv_rn(1.5f, tb0), q1 = __fdiv_rn(1.5f, tb1);
    thr = __fsqrt_rn(__fadd_rn(__fmul_rn(q0, q0), __fmul_rn(q1, q1)));
}

// ---------------------------------------------------------------------------
// K1: fused nearest-GT + key build. grid (16 pc, 16 b) x 512.
// Thread (gs=tid>>6, sub=tid&63) scans GT slice [gs*128, gs*128+128) for
// position i = pc*64+sub; 8-way LDS min-tree on packed ((u64)cd_bits<<10)|g
// reproduces np.argmin first-index tie rule (min over g, cd>0 => bit-monotone).
// gs==0 lanes build sort key / sem class / tb init / closs partial.
// ---------------------------------------------------------------------------
__global__ __launch_bounds__(512) void k_near(
    const float* __restrict__ positions, const float* __restrict__ gt_pts,
    const int* __restrict__ gt_ins, const int* __restrict__ gt_order,
    const int* __restrict__ gt_type,
    int* __restrict__ key_ws, int* __restrict__ sem_ws,
    int* __restrict__ tb_ws, float* __restrict__ closs_part)
{
    __shared__ float2 sp[GG];
    __shared__ unsigned long long pl[512];
    const int b = blockIdx.y, pc = blockIdx.x, tid = threadIdx.x;
    const int sub = tid & 63, gs = tid >> 6;
    float bnd0, bnd1, tb0, tb1, thr;
    get_consts(bnd0, bnd1, tb0, tb1, thr);

    for (int g = tid; g < GG; g += 512) {
        float2 gp = ((const float2*)gt_pts)[b * GG + g];
        float2 pg;
        pg.x = __fdiv_rn(__fadd_rn(gp.x, bnd0), tb0);
        pg.y = __fdiv_rn(__fadd_rn(gp.y, bnd1), tb1);
        sp[g] = pg;
    }
    __syncthreads();

    const int i = (pc << 6) + sub;
    float2 p = ((const float2*)positions)[b * NN + i];
    const float px = __fdiv_rn(p.x, 399.0f);
    const float py = __fdiv_rn(p.y, 199.0f);

    unsigned long long best = ~0ull;
    const int gbase = gs << 7;
    #pragma unroll 8
    for (int j = 0; j < 128; ++j) {
        float2 pg = sp[gbase + j];
        float dx = __fsub_rn(px, pg.x);
        float dy = __fsub_rn(py, pg.y);
        float s  = __fadd_rn(__fadd_rn(__fmul_rn(dx, dx), __fmul_rn(dy, dy)), 1e-12f);
        float cd = __fsqrt_rn(s);
        unsigned long long pk =
            ((unsigned long long)__float_as_uint(cd) << 10) | (unsigned)(gbase + j);
        best = (pk < best) ? pk : best;
    }
    pl[tid] = best;
    __syncthreads();
    #pragma unroll
    for (int s = 4; s > 0; s >>= 1) {
        if (gs < s) {
            unsigned long long v = pl[tid + (s << 6)];
            if (v < pl[tid]) pl[tid] = v;
        }
        __syncthreads();
    }

    if (tid < 64) {
        best = pl[tid];
        const int bi = (int)(best & 1023u);
        const float cd = __uint_as_float((unsigned)(best >> 10));

        const int ins = (cd < thr) ? gt_ins[b * GG + bi] : -1;
        const int key = ((ins + 1) << 15) | (gt_order[b * GG + bi] << 10) | i;
        key_ws[(b << 10) + i] = key;
        sem_ws[(b << 10) + i] = gt_type[b * GG + bi];
        tb_ws[(b << 10) + i] = NN;   // default: no incoming edge (k_link overwrites)

        float2 pg = sp[bi];
        float cl = fabsf(__fsub_rn(px, pg.x)) + fabsf(__fsub_rn(py, pg.y));
        #pragma unroll
        for (int s = 32; s > 0; s >>= 1) cl += __shfl_down(cl, s);
        if (tid == 0) closs_part[(b << 4) + pc] = cl;
    }
}

// ---------------------------------------------------------------------------
// K2: successor-link. grid (8 pc, 16 b) x 128.
// Sorted-consecutive pair == (key, min{key_j > key}); same ins (>=0) -> edge.
// Replaces rank-sort + edges kernels (the only use of the lexsort was
// consecutive pairs). newblk == blk identity (each blk column has <=1
// nonzero) makes the reference's dist_map/argmin re-selection a no-op.
// Block (0,0) also folds closs partials into out[0] and zeroes out[1..2]
// (k_out accumulates into them afterwards; stream order = no race).
// ---------------------------------------------------------------------------
__global__ __launch_bounds__(128) void k_link(
    const int* __restrict__ key_ws,
    int* __restrict__ tf_ws, int* __restrict__ tb_ws,
    const float* __restrict__ closs_part, float* __restrict__ out)
{
    __shared__ int sk[NN];
    __shared__ float rcl[128];
    const int b = blockIdx.y, pc = blockIdx.x, tid = threadIdx.x;
    for (int j = tid; j < NN; j += 128) sk[j] = key_ws[(b << 10) + j];
    __syncthreads();

    const int k = sk[(pc << 7) + tid];
    int succ = 0x7fffffff;
    const int4* sk4 = (const int4*)sk;
    #pragma unroll 8
    for (int j = 0; j < 256; ++j) {
        int4 v = sk4[j];
        succ = min(succ, (v.x > k) ? v.x : 0x7fffffff);
        succ = min(succ, (v.y > k) ? v.y : 0x7fffffff);
        succ = min(succ, (v.z > k) ? v.z : 0x7fffffff);
        succ = min(succ, (v.w > k) ? v.w : 0x7fffffff);
    }
    const int i = k & 1023;
    const bool edge = (succ != 0x7fffffff) &&
                      ((succ >> 15) == (k >> 15)) && ((k >> 15) >= 1);
    tf_ws[(b << 10) + i] = edge ? (succ & 1023) : NN;
    if (edge) tb_ws[(b << 10) + (succ & 1023)] = i;

    if (b == 0 && pc == 0) {
        rcl[tid] = closs_part[tid] + closs_part[tid + 128];
        __syncthreads();
        for (int s = 64; s > 0; s >>= 1) {
            if (tid < s) rcl[tid] += rcl[tid + s];
            __syncthreads();
        }
        if (tid == 0) {
            out[0] = (float)((double)rcl[0] / 32768.0);
            out[1] = 0.f;
            out[2] = 0.f;
        }
    }
}

// ---------------------------------------------------------------------------
// K3: fused M writer. grid (32 pc, 16 b) x 256.
// Phase A: zero the block's 32-row slab of M densely (float4, coalesced).
// Phase B: ones at (i, tf[i]); dense row-N from tb; sg one-hot; wave-reduce
// mloss/semloss and atomicAdd pre-scaled partials into out[1..2].
// ---------------------------------------------------------------------------
__global__ __launch_bounds__(256) void k_out(
    const float* __restrict__ matches, const float* __restrict__ semantics,
    const int* __restrict__ sem_ws,
    const int* __restrict__ tf_ws, const int* __restrict__ tb_ws,
    float* __restrict__ out)
{
    const int b = blockIdx.y, pc = blockIdx.x, tid = threadIdx.x;
    float* Mb = out + 3 + (size_t)b * NP1 * NP1;

    // Phase A: zero rows [pc*32, pc*32+32) = 32*1025 floats
    {
        float* base = Mb + (size_t)pc * 32 * NP1;
        const int total = 32 * NP1;                       // 32800
        const int mis = (int)(((size_t)base >> 2) & 3);
        const int head = (4 - mis) & 3;
        const int n4 = (total - head) >> 2;
        const int tail = total - head - (n4 << 2);
        if (tid < head) base[tid] = 0.f;
        float4* b4 = (float4*)(base + head);
        float4 z; z.x = 0.f; z.y = 0.f; z.z = 0.f; z.w = 0.f;
        for (int k = tid; k < n4; k += 256) b4[k] = z;
        if (tid < tail) base[head + (n4 << 2) + tid] = 0.f;
    }
    __syncthreads();

    // Phase B: first wave handles the block's 32 rows/columns
    if (tid < 64) {
        double mv = 0.0, sv = 0.0;
        if (tid < 32) {
            const int i = (pc << 5) + tid;
            const int jf = tf_ws[(b << 10) + i];
            const int jb = tb_ws[(b << 10) + i];

            Mb[(size_t)i * NP1 + jf] = 1.0f;                       // row i
            Mb[(size_t)NN * NP1 + i] = (jb == NN) ? 1.0f : 0.0f;   // row N dense
            if (pc == 0 && tid == 0) Mb[(size_t)NN * NP1 + NN] = 0.f;

            const float* mrow = matches + (size_t)b * NP1 * NP1 + (size_t)i * NP1;
            mv = (double)mrow[jf] + (double)mrow[jb];

            const int sc = sem_ws[(b << 10) + i];
            sv = (double)semantics[(b * NC + sc) * NN + i];

            float* sg = out + 3 + (size_t)BB * NP1 * NP1 + (size_t)b * NC * NN;
            sg[0 * NN + i] = (sc == 0) ? 1.0f : 0.0f;
            sg[1 * NN + i] = (sc == 1) ? 1.0f : 0.0f;
            sg[2 * NN + i] = (sc == 2) ? 1.0f : 0.0f;
        }
        #pragma unroll
        for (int s = 32; s > 0; s >>= 1) {
            mv += __shfl_down(mv, s);
            sv += __shfl_down(sv, s);
        }
        if (tid == 0) {
            atomicAdd(out + 1, (float)(-mv / 16384.0));
            atomicAdd(out + 2, (float)(-sv / 16384.0));
        }
    }
}

extern "C" void kernel_launch(void* const* d_in, const int* in_sizes, int n_in,
                              void* d_out, int out_size, void* d_ws, size_t ws_size,
                              hipStream_t stream) {
    const float* matches   = (const float*)d_in[0];
    const float* positions = (const float*)d_in[1];
    const float* semantics = (const float*)d_in[2];
    // d_in[3] = masks (all ones, unused)
    const float* gt_pts    = (const float*)d_in[4];
    const int*   gt_ins    = (const int*)d_in[5];
    const int*   gt_order  = (const int*)d_in[6];
    const int*   gt_type   = (const int*)d_in[7];
    float* out = (float*)d_out;

    char* ws = (char*)d_ws;
    int*    key_ws     = (int*)(ws + 0 * 65536);
    int*    sem_ws     = (int*)(ws + 1 * 65536);
    int*    tf_ws      = (int*)(ws + 2 * 65536);
    int*    tb_ws      = (int*)(ws + 3 * 65536);
    float*  closs_part = (float*)(ws + 4 * 65536);   // 256 floats

    hipLaunchKernelGGL(k_near, dim3(16, 16), dim3(512), 0, stream,
                       positions, gt_pts, gt_ins, gt_order, gt_type,
                       key_ws, sem_ws, tb_ws, closs_part);
    hipLaunchKernelGGL(k_link, dim3(8, 16),  dim3(128), 0, stream,
                       key_ws, tf_ws, tb_ws, closs_part, out);
    hipLaunchKernelGGL(k_out,  dim3(32, 16), dim3(256), 0, stream,
                       matches, semantics, sem_ws, tf_ws, tb_ws, out);
}

// Round 5
// 150.404 us; speedup vs baseline: 1.0526x; 1.0526x over previous
//
#include <hip/hip_runtime.h>
#include <math.h>

#define BB 16
#define NN 1024
#define GG 1024
#define NP1 1025
#define NC 3

// Constants replicated with numpy's exact f32 op sequence (verified absmax=0 R1-R4)
__device__ __forceinline__ void get_consts(float& bnd0, float& bnd1,
                                           float& tb0, float& tb1, float& thr) {
    const float bx0 = (float)(-30.0 + 0.15 / 2.0);
    const float bx1 = (float)(-15.0 + 0.15 / 2.0);
    bnd0 = __fsub_rn(__fmul_rn(0.15f, 0.5f), bx0);
    bnd1 = __fsub_rn(__fmul_rn(0.15f, 0.5f), bx1);
    tb0 = __fmul_rn(2.0f, bnd0); tb1 = __fmul_rn(2.0f, bnd1);
    const float q0 = __fdiv_rn(1.5f, tb0), q1 = __fdiv_rn(1.5f, tb1);
    thr = __fsqrt_rn(__fadd_rn(__fmul_rn(q0, q0), __fmul_rn(q1, q1)));
}

// ---------------------------------------------------------------------------
// K1: fused nearest-GT + key build. grid (16 pc, 16 b) x 512.
// Thread (gs=tid>>6, sub=tid&63) scans GT slice [gs*128, gs*128+128) for
// position i = pc*64+sub; 8-way LDS min-tree on packed ((u64)cd_bits<<10)|g
// reproduces np.argmin first-index tie rule (min over g, cd>0 => bit-monotone).
// gs==0 lanes build sort key / sem class / tb init / closs partial.
// ---------------------------------------------------------------------------
__global__ __launch_bounds__(512) void k_near(
    const float* __restrict__ positions, const float* __restrict__ gt_pts,
    const int* __restrict__ gt_ins, const int* __restrict__ gt_order,
    const int* __restrict__ gt_type,
    int* __restrict__ key_ws, int* __restrict__ sem_ws,
    int* __restrict__ tb_ws, float* __restrict__ closs_part)
{
    __shared__ float2 sp[GG];
    __shared__ unsigned long long pl[512];
    const int b = blockIdx.y, pc = blockIdx.x, tid = threadIdx.x;
    const int sub = tid & 63, gs = tid >> 6;
    float bnd0, bnd1, tb0, tb1, thr;
    get_consts(bnd0, bnd1, tb0, tb1, thr);

    for (int g = tid; g < GG; g += 512) {
        float2 gp = ((const float2*)gt_pts)[b * GG + g];
        float2 pg;
        pg.x = __fdiv_rn(__fadd_rn(gp.x, bnd0), tb0);
        pg.y = __fdiv_rn(__fadd_rn(gp.y, bnd1), tb1);
        sp[g] = pg;
    }
    __syncthreads();

    const int i = (pc << 6) + sub;
    float2 p = ((const float2*)positions)[b * NN + i];
    const float px = __fdiv_rn(p.x, 399.0f);
    const float py = __fdiv_rn(p.y, 199.0f);

    unsigned long long best = ~0ull;
    const int gbase = gs << 7;
    #pragma unroll 8
    for (int j = 0; j < 128; ++j) {
        float2 pg = sp[gbase + j];
        float dx = __fsub_rn(px, pg.x);
        float dy = __fsub_rn(py, pg.y);
        float s  = __fadd_rn(__fadd_rn(__fmul_rn(dx, dx), __fmul_rn(dy, dy)), 1e-12f);
        float cd = __fsqrt_rn(s);
        unsigned long long pk =
            ((unsigned long long)__float_as_uint(cd) << 10) | (unsigned)(gbase + j);
        best = (pk < best) ? pk : best;
    }
    pl[tid] = best;
    __syncthreads();
    #pragma unroll
    for (int s = 4; s > 0; s >>= 1) {
        if (gs < s) {
            unsigned long long v = pl[tid + (s << 6)];
            if (v < pl[tid]) pl[tid] = v;
        }
        __syncthreads();
    }

    if (tid < 64) {
        best = pl[tid];
        const int bi = (int)(best & 1023u);
        const float cd = __uint_as_float((unsigned)(best >> 10));

        const int ins = (cd < thr) ? gt_ins[b * GG + bi] : -1;
        const int key = ((ins + 1) << 15) | (gt_order[b * GG + bi] << 10) | i;
        key_ws[(b << 10) + i] = key;
        sem_ws[(b << 10) + i] = gt_type[b * GG + bi];
        tb_ws[(b << 10) + i] = NN;   // default: no incoming edge (k_link overwrites)

        float2 pg = sp[bi];
        float cl = fabsf(__fsub_rn(px, pg.x)) + fabsf(__fsub_rn(py, pg.y));
        #pragma unroll
        for (int s = 32; s > 0; s >>= 1) cl += __shfl_down(cl, s);
        if (tid == 0) closs_part[(b << 4) + pc] = cl;
    }
}

// ---------------------------------------------------------------------------
// K2: successor-link. grid (8 pc, 16 b) x 128.
// Sorted-consecutive pair == (key, min{key_j > key}); same ins (>=0) -> edge.
// Replaces rank-sort + edges kernels (the only use of the lexsort was
// consecutive pairs). newblk == blk identity (each blk column has <=1
// nonzero) makes the reference's dist_map/argmin re-selection a no-op.
// ---------------------------------------------------------------------------
__global__ __launch_bounds__(128) void k_link(
    const int* __restrict__ key_ws,
    int* __restrict__ tf_ws, int* __restrict__ tb_ws)
{
    __shared__ int sk[NN];
    const int b = blockIdx.y, pc = blockIdx.x, tid = threadIdx.x;
    for (int j = tid; j < NN; j += 128) sk[j] = key_ws[(b << 10) + j];
    __syncthreads();

    const int k = sk[(pc << 7) + tid];
    int succ = 0x7fffffff;
    const int4* sk4 = (const int4*)sk;
    #pragma unroll 8
    for (int j = 0; j < 256; ++j) {
        int4 v = sk4[j];
        succ = min(succ, (v.x > k) ? v.x : 0x7fffffff);
        succ = min(succ, (v.y > k) ? v.y : 0x7fffffff);
        succ = min(succ, (v.z > k) ? v.z : 0x7fffffff);
        succ = min(succ, (v.w > k) ? v.w : 0x7fffffff);
    }
    const int i = k & 1023;
    const bool edge = (succ != 0x7fffffff) &&
                      ((succ >> 15) == (k >> 15)) && ((k >> 15) >= 1);
    tf_ws[(b << 10) + i] = edge ? (succ & 1023) : NN;
    if (edge) tb_ws[(b << 10) + (succ & 1023)] = i;
}

// ---------------------------------------------------------------------------
// K3: fused M writer. grid (32 pc, 16 b) x 256.
// Phase A: zero the block's 32-row slab of M densely (float4, coalesced).
// Phase B: ones at (i, tf[i]); dense row-N from tb; sg one-hot; wave-reduce
// mloss/semloss partials to workspace (NO same-address atomics — R4's
// 512-block atomicAdd on out[1..2] cost ~10 us of line ping-pong).
// ---------------------------------------------------------------------------
__global__ __launch_bounds__(256) void k_out(
    const float* __restrict__ matches, const float* __restrict__ semantics,
    const int* __restrict__ sem_ws,
    const int* __restrict__ tf_ws, const int* __restrict__ tb_ws,
    float* __restrict__ out, double* __restrict__ mpart, double* __restrict__ spart)
{
    const int b = blockIdx.y, pc = blockIdx.x, tid = threadIdx.x;
    float* Mb = out + 3 + (size_t)b * NP1 * NP1;

    // Phase A: zero rows [pc*32, pc*32+32) = 32*1025 floats
    {
        float* base = Mb + (size_t)pc * 32 * NP1;
        const int total = 32 * NP1;                       // 32800
        const int mis = (int)(((size_t)base >> 2) & 3);
        const int head = (4 - mis) & 3;
        const int n4 = (total - head) >> 2;
        const int tail = total - head - (n4 << 2);
        if (tid < head) base[tid] = 0.f;
        float4* b4 = (float4*)(base + head);
        float4 z; z.x = 0.f; z.y = 0.f; z.z = 0.f; z.w = 0.f;
        for (int k = tid; k < n4; k += 256) b4[k] = z;
        if (tid < tail) base[head + (n4 << 2) + tid] = 0.f;
    }
    __syncthreads();

    // Phase B: first wave handles the block's 32 rows/columns
    if (tid < 64) {
        double mv = 0.0, sv = 0.0;
        if (tid < 32) {
            const int i = (pc << 5) + tid;
            const int jf = tf_ws[(b << 10) + i];
            const int jb = tb_ws[(b << 10) + i];

            Mb[(size_t)i * NP1 + jf] = 1.0f;                       // row i
            Mb[(size_t)NN * NP1 + i] = (jb == NN) ? 1.0f : 0.0f;   // row N dense
            if (pc == 0 && tid == 0) Mb[(size_t)NN * NP1 + NN] = 0.f;

            const float* mrow = matches + (size_t)b * NP1 * NP1 + (size_t)i * NP1;
            mv = (double)mrow[jf] + (double)mrow[jb];

            const int sc = sem_ws[(b << 10) + i];
            sv = (double)semantics[(b * NC + sc) * NN + i];

            float* sg = out + 3 + (size_t)BB * NP1 * NP1 + (size_t)b * NC * NN;
            sg[0 * NN + i] = (sc == 0) ? 1.0f : 0.0f;
            sg[1 * NN + i] = (sc == 1) ? 1.0f : 0.0f;
            sg[2 * NN + i] = (sc == 2) ? 1.0f : 0.0f;
        }
        #pragma unroll
        for (int s = 32; s > 0; s >>= 1) {
            mv += __shfl_down(mv, s);
            sv += __shfl_down(sv, s);
        }
        if (tid == 0) {
            mpart[(b << 5) + pc] = mv;
            spart[(b << 5) + pc] = sv;
        }
    }
}

// ---------------------------------------------------------------------------
// K4: fold partials (256 closs, 512 m, 512 s) into the 3 scalars.
// ---------------------------------------------------------------------------
__global__ __launch_bounds__(512) void k_final(
    const float* __restrict__ closs_part, const double* __restrict__ mpart,
    const double* __restrict__ spart, float* __restrict__ out)
{
    __shared__ double rc[512], rm[512], rs[512];
    const int t = threadIdx.x;
    rc[t] = (t < 256) ? (double)closs_part[t] : 0.0;
    rm[t] = mpart[t]; rs[t] = spart[t];
    __syncthreads();
    for (int s = 256; s > 0; s >>= 1) {
        if (t < s) { rc[t] += rc[t + s]; rm[t] += rm[t + s]; rs[t] += rs[t + s]; }
        __syncthreads();
    }
    if (t == 0) {
        out[0] = (float)(rc[0] / 32768.0);    // mean over B of (sum/2048)
        out[1] = (float)(-rm[0] / 16384.0);   // mean over B of (sum_f + sum_b)/1024
        out[2] = (float)(-rs[0] / 16384.0);
    }
}

extern "C" void kernel_launch(void* const* d_in, const int* in_sizes, int n_in,
                              void* d_out, int out_size, void* d_ws, size_t ws_size,
                              hipStream_t stream) {
    const float* matches   = (const float*)d_in[0];
    const float* positions = (const float*)d_in[1];
    const float* semantics = (const float*)d_in[2];
    // d_in[3] = masks (all ones, unused)
    const float* gt_pts    = (const float*)d_in[4];
    const int*   gt_ins    = (const int*)d_in[5];
    const int*   gt_order  = (const int*)d_in[6];
    const int*   gt_type   = (const int*)d_in[7];
    float* out = (float*)d_out;

    char* ws = (char*)d_ws;
    int*    key_ws     = (int*)(ws + 0 * 65536);
    int*    sem_ws     = (int*)(ws + 1 * 65536);
    int*    tf_ws      = (int*)(ws + 2 * 65536);
    int*    tb_ws      = (int*)(ws + 3 * 65536);
    float*  closs_part = (float*)(ws + 4 * 65536);            // 256 floats
    double* mpart      = (double*)(ws + 4 * 65536 + 4096);    // 512 doubles
    double* spart      = (double*)(ws + 4 * 65536 + 8192);    // 512 doubles

    hipLaunchKernelGGL(k_near,  dim3(16, 16), dim3(512), 0, stream,
                       positions, gt_pts, gt_ins, gt_order, gt_type,
                       key_ws, sem_ws, tb_ws, closs_part);
    hipLaunchKernelGGL(k_link,  dim3(8, 16),  dim3(128), 0, stream,
                       key_ws, tf_ws, tb_ws);
    hipLaunchKernelGGL(k_out,   dim3(32, 16), dim3(256), 0, stream,
                       matches, semantics, sem_ws, tf_ws, tb_ws, out, mpart, spart);
    hipLaunchKernelGGL(k_final, dim3(1),      dim3(512), 0, stream,
                       closs_part, mpart, spart, out);
}